// Round 7
// baseline (347.205 us; speedup 1.0000x reference)
//
#include <hip/hip_runtime.h>

#define NN 10000
#define BB 8
#define EE 160000
#define DH 128
#define LN_EPS 1e-5f

typedef unsigned short ushort_t;
typedef unsigned int uint_t;

typedef __bf16 bf16x8 __attribute__((ext_vector_type(8)));
typedef float floatx4 __attribute__((ext_vector_type(4)));
typedef float floatx2 __attribute__((ext_vector_type(2)));

__device__ __forceinline__ float b2f(uint_t u) { return __uint_as_float(u << 16); }
__device__ __forceinline__ ushort_t f2b(float f) {
    uint_t u = __float_as_uint(f);
    return (ushort_t)((u + 0x7fffu + ((u >> 16) & 1u)) >> 16);
}
__device__ __forceinline__ uint_t pack2(float lo, float hi) {
    return (uint_t)f2b(lo) | ((uint_t)f2b(hi) << 16);
}
__device__ __forceinline__ float sigm(float x) { return 1.0f / (1.0f + __expf(-x)); }
__device__ __forceinline__ float tanh_fast(float x) {
    float ex = __expf(2.0f * x);
    return 1.0f - 2.0f / (ex + 1.0f);
}

// unpack u32 holding 2 bf16 -> float2
__device__ __forceinline__ floatx2 unpk(uint_t u) {
    floatx2 r;
    r.x = __uint_as_float(u << 16);
    r.y = __uint_as_float(u & 0xffff0000u);
    return r;
}
// packed dual-FMA: a += w * v  (one VALU inst per 2 floats)
__device__ __forceinline__ void pk_fma(floatx2& a, floatx2 w, floatx2 v) {
    asm("v_pk_fma_f32 %0, %1, %2, %0" : "+v"(a) : "v"(w), "v"(v));
}
// accumulate 8 bf16 (uint4) with packed weight w2: 8 unpack + 4 pk_fma
__device__ __forceinline__ void acc8p(floatx2* a, floatx2 w2, uint4 v) {
    pk_fma(a[0], w2, unpk(v.x));
    pk_fma(a[1], w2, unpk(v.y));
    pk_fma(a[2], w2, unpk(v.z));
    pk_fma(a[3], w2, unpk(v.w));
}

// ---------------- CSR build ----------------

__global__ void count_deg(const int* __restrict__ ei, int* __restrict__ cnt) {
    int e = blockIdx.x * 256 + threadIdx.x;
    if (e < EE) atomicAdd(&cnt[ei[EE + e]], 1);
}

__global__ __launch_bounds__(256) void scan1(const int* __restrict__ cnt,
                                             int* __restrict__ offs,
                                             int* __restrict__ bsum) {
    __shared__ int s[256];
    const int t = threadIdx.x, idx = blockIdx.x * 256 + t;
    int x = (idx < NN) ? cnt[idx] : 0;
    s[t] = x;
    __syncthreads();
    for (int o = 1; o < 256; o <<= 1) {
        int v = s[t];
        int u = (t >= o) ? s[t - o] : 0;
        __syncthreads();
        s[t] = v + u;
        __syncthreads();
    }
    if (idx < NN) offs[idx] = s[t] - x;  // block-local exclusive
    if (t == 255) bsum[blockIdx.x] = s[255];
}

// scan3: cross-block prefix + dis + degree histogram (64 buckets) for the sort
__global__ __launch_bounds__(256) void scan3(const int* __restrict__ cnt,
                                             const int* __restrict__ bsum,
                                             int* __restrict__ offs,
                                             int* __restrict__ cursor,
                                             float* __restrict__ dis,
                                             int* __restrict__ hist) {
    __shared__ int sb[40];
    __shared__ int pfx;
    const int t = threadIdx.x;
    if (t < 40) sb[t] = bsum[t];
    __syncthreads();
    if (t == 0) {
        int a = 0;
        for (int i = 0; i < blockIdx.x; ++i) a += sb[i];
        pfx = a;
    }
    __syncthreads();
    const int idx = blockIdx.x * 256 + t;
    if (idx < NN) {
        int off = offs[idx] + pfx;
        offs[idx] = off;
        cursor[idx] = off;
        int d = cnt[idx];
        dis[idx] = rsqrtf((float)(d + 1));
        atomicAdd(&hist[d < 63 ? d : 63], 1);
    }
    if (idx == 0) offs[NN] = EE;
}

// exclusive prefix of the 64-bucket histogram -> bucket cursors
__global__ __launch_bounds__(64) void bucket_scan(const int* __restrict__ hist,
                                                  int* __restrict__ bcur) {
    if (threadIdx.x == 0) {
        int a = 0;
        for (int i = 0; i < 64; ++i) {
            int v = hist[i];
            bcur[i] = a;
            a += v;
        }
    }
}

// scatter nodes into degree-sorted order (scheduling permutation only)
__global__ __launch_bounds__(256) void order_k(const int* __restrict__ offs,
                                               int* __restrict__ bcur,
                                               int* __restrict__ order) {
    int idx = blockIdx.x * 256 + threadIdx.x;
    if (idx < NN) {
        int d = offs[idx + 1] - offs[idx];
        int pos = atomicAdd(&bcur[d < 63 ? d : 63], 1);
        order[pos] = idx;
    }
}

// csr packed: bf16(dis[src])<<16 | src   (src < 16384 fits 14 bits)
__global__ void fill_csr(const int* __restrict__ ei, int* __restrict__ cursor,
                         const float* __restrict__ dis, int* __restrict__ csr_pk) {
    int e = blockIdx.x * 256 + threadIdx.x;
    if (e < EE) {
        int s = ei[e];
        int d = ei[EE + e];
        int pos = atomicAdd(&cursor[d], 1);
        csr_pk[pos] = (int)(((uint_t)f2b(dis[s]) << 16) | (uint_t)s);
    }
}

// ---------------- pack x,h -> bf16 + weight transpose (merged) ----------------

__global__ __launch_bounds__(256) void packwt_k(const float* __restrict__ x,
                                                const float* __restrict__ h,
                                                ushort_t* __restrict__ xb,
                                                ushort_t* __restrict__ hb,
                                                const float* __restrict__ Wz,
                                                const float* __restrict__ Wr,
                                                const float* __restrict__ Wc,
                                                ushort_t* __restrict__ Wt_zr,
                                                ushort_t* __restrict__ Wt_c) {
    if (blockIdx.x < 10000) {
        const size_t o = ((size_t)blockIdx.x * 256 + threadIdx.x) * 4;
        float4 vx = *(const float4*)(x + o);
        uint2 px;
        px.x = pack2(vx.x, vx.y);
        px.y = pack2(vx.z, vx.w);
        *(uint2*)(xb + o) = px;
        float4 vh = *(const float4*)(h + o);
        uint2 ph;
        ph.x = pack2(vh.x, vh.y);
        ph.y = pack2(vh.z, vh.w);
        *(uint2*)(hb + o) = ph;
    } else {
        const int col = blockIdx.x - 10000, k = threadIdx.x;
        if (col < 256) {
            float v = (col < 128) ? Wz[(size_t)k * 128 + col]
                                  : Wr[(size_t)k * 128 + col - 128];
            Wt_zr[(size_t)col * 256 + k] = f2b(v);
        } else {
            int c2 = col - 256;
            Wt_c[(size_t)c2 * 256 + k] = f2b(Wc[(size_t)k * 128 + c2]);
        }
    }
}

// ---------------- gather16: 4 waves x 4 nodes/wave, 16 lanes per node -------------
// dst[b,n] = dis[n] * ( sum_e dis[s]*src[b,s] + dis[n]*src[b,n] )
// One 16-lane group per node: lane il owns cols il*8..il*8+7, accumulates ALL edges
// of its node -> lane-private result, no cross-lane reduce. b = blockIdx&7 keeps
// XCD/L2 batch sharding (FETCH ~104 MB). Packed CSR word (w<<16|src) -> ONE
// bpermute per edge; junk slots broadcast 0 -> weight 0.0 -> no predication.
// Nodes are processed in DEGREE-SORTED order: the wave's 4 nodes have ~equal
// degree, so the dmax loop bound ~= each node's own degree (junk slots ~25% -> ~5%).

template <int NB>
__global__ __launch_bounds__(256) void gather16(
    const ushort_t* __restrict__ src0, const ushort_t* __restrict__ src1,
    const int* __restrict__ offs, const int* __restrict__ csr_pk,
    const float* __restrict__ dis, const int* __restrict__ order,
    ushort_t* __restrict__ dst0, ushort_t* __restrict__ dst1) {
    const int tid = threadIdx.x, lane = tid & 63;
    const int b = blockIdx.x & 7;
    const int g = lane >> 4, il = lane & 15;
    const int slot = (blockIdx.x >> 3) * 16 + (tid >> 6) * 4 + g;
    const int ng = order[slot];  // my group's node (degree-sorted schedule)
    const ushort_t* base0 = src0 + (size_t)b * NN * 128;
    const ushort_t* base1 = (NB == 2) ? (src1 + (size_t)b * NN * 128) : base0;
    const uint_t cofs = (uint_t)il * 8u;

    floatx2 a0[4], a1[4];
#pragma unroll
    for (int j = 0; j < 4; ++j) {
        a0[j] = (floatx2){0.f, 0.f};
        a1[j] = (floatx2){0.f, 0.f};
    }

    const int e0 = offs[ng], e1 = offs[ng + 1];
    const float dn = dis[ng];

    {  // self row, weight dn inside the sum
        const floatx2 d2 = {dn, dn};
        const uint_t off = (uint_t)ng * 128u + cofs;
        acc8p(a0, d2, *(const uint4*)(base0 + off));
        if (NB == 2) acc8p(a1, d2, *(const uint4*)(base1 + off));
    }

    // max degree over the wave's 4 groups -> uniform loop bound (~deg after sort)
    int mx = e1 - e0;
    mx = max(mx, __shfl_xor(mx, 16));
    mx = max(mx, __shfl_xor(mx, 32));
    const int dmax = __builtin_amdgcn_readfirstlane(mx);
    const int pbase = (lane & 48) << 2;  // bpermute byte base of group's lane 0

    for (int ibase = 0; ibase < dmax; ibase += 16) {
        // refill: lane il of group g holds packed edge e0+ibase+il (0 if past end)
        int pk = 0;
        const int pos = e0 + ibase + il;
        if (pos < e1) pk = csr_pk[pos];
        const int lim = (dmax - ibase) < 16 ? (dmax - ibase) : 16;
        int pidx = pbase;
#pragma unroll 1
        for (int i = 0; i < lim; i += 4) {
            // metadata for 4 edges (junk slots -> pk=0 -> w=0, row 0)
            const int p0 = __builtin_amdgcn_ds_bpermute(pidx, pk);
            const int p1 = __builtin_amdgcn_ds_bpermute(pidx + 4, pk);
            const int p2 = __builtin_amdgcn_ds_bpermute(pidx + 8, pk);
            const int p3 = __builtin_amdgcn_ds_bpermute(pidx + 12, pk);
            pidx += 16;
            const uint_t q0 = (uint_t)(p0 & 0xffff) * 128u + cofs;
            const uint_t q1 = (uint_t)(p1 & 0xffff) * 128u + cofs;
            const uint_t q2 = (uint_t)(p2 & 0xffff) * 128u + cofs;
            const uint_t q3 = (uint_t)(p3 & 0xffff) * 128u + cofs;
            // issue ALL loads before any FMA: 8 in flight (NB=2)
            uint4 v0 = *(const uint4*)(base0 + q0);
            uint4 v1 = *(const uint4*)(base0 + q1);
            uint4 v2 = *(const uint4*)(base0 + q2);
            uint4 v3 = *(const uint4*)(base0 + q3);
            uint4 u0, u1, u2, u3;
            if (NB == 2) {
                u0 = *(const uint4*)(base1 + q0);
                u1 = *(const uint4*)(base1 + q1);
                u2 = *(const uint4*)(base1 + q2);
                u3 = *(const uint4*)(base1 + q3);
            }
            const float f0 = __uint_as_float((uint_t)p0 & 0xffff0000u);
            const float f1 = __uint_as_float((uint_t)p1 & 0xffff0000u);
            const float f2 = __uint_as_float((uint_t)p2 & 0xffff0000u);
            const float f3 = __uint_as_float((uint_t)p3 & 0xffff0000u);
            const floatx2 w0 = {f0, f0}, w1 = {f1, f1}, w2 = {f2, f2}, w3 = {f3, f3};
            acc8p(a0, w0, v0);
            acc8p(a0, w1, v1);
            acc8p(a0, w2, v2);
            acc8p(a0, w3, v3);
            if (NB == 2) {
                acc8p(a1, w0, u0);
                acc8p(a1, w1, u1);
                acc8p(a1, w2, u2);
                acc8p(a1, w3, u3);
            }
        }
    }

    // lane-private result: scale by dn, pack, store (all 64 lanes)
    const size_t o = ((size_t)b * NN + ng) * 128 + cofs;
    uint4 st;
    st.x = pack2(a0[0].x * dn, a0[0].y * dn);
    st.y = pack2(a0[1].x * dn, a0[1].y * dn);
    st.z = pack2(a0[2].x * dn, a0[2].y * dn);
    st.w = pack2(a0[3].x * dn, a0[3].y * dn);
    *(uint4*)(dst0 + o) = st;
    if (NB == 2) {
        uint4 st1;
        st1.x = pack2(a1[0].x * dn, a1[0].y * dn);
        st1.y = pack2(a1[1].x * dn, a1[1].y * dn);
        st1.z = pack2(a1[2].x * dn, a1[2].y * dn);
        st1.w = pack2(a1[3].x * dn, a1[3].y * dn);
        *(uint4*)(dst1 + o) = st1;
    }
}

// ---------------- GEMM 128x128 tile, K=256 = [A1 | A2] @ Wt, fused epilogues ------
// 512 threads / 8 waves: wave w owns rows w*16..w*16+15 (acc = 8 x floatx4).
// Register-prefetch pipeline: k0+1's global loads issued before k0's MFMA compute,
// consumed by ds_write after the next barrier -> HBM latency hidden under compute.
// PHASE 0: mode=blockIdx.y (0: z=sigma->z_buf bf16; 1: r=sigma, rh=r*h->rh bf16)
// PHASE 1: mode 2: tanh, GRU blend, LayerNorm -> out f32

template <int PHASE>
__global__ __launch_bounds__(512) void gemm_k(
    const ushort_t* __restrict__ A1, const ushort_t* __restrict__ A2,
    const ushort_t* __restrict__ Wt, const float* __restrict__ bz,
    const float* __restrict__ br, const float* __restrict__ bc,
    const float* __restrict__ h_prev, const ushort_t* __restrict__ z_in,
    const float* __restrict__ gamma, const float* __restrict__ beta,
    ushort_t* __restrict__ z_out, ushort_t* __restrict__ rh_out,
    float* __restrict__ f_out) {
    __shared__ __align__(16) ushort_t As[128 * 72];
    __shared__ __align__(16) ushort_t Bs[128 * 72];
    const int tid = threadIdx.x;
    const int rb0 = blockIdx.x * 128;
    const int mode = (PHASE == 1) ? 2 : blockIdx.y;
    const int cb0 = (mode == 1) ? 128 : 0;

    const int wv = tid >> 6, lane = tid & 63;
    const int l15 = lane & 15, q = lane >> 4;
    const int sr = tid >> 2;        // 0..127: A row / B col staged by this thread
    const int kh = (tid & 3) * 16;  // 16-element K chunk

    floatx4 acc[8];
#pragma unroll
    for (int j = 0; j < 8; ++j) acc[j] = (floatx4){0.f, 0.f, 0.f, 0.f};

    uint4 pa0, pa1, pb0, pb1;  // prefetch registers (one K-step tile slice)
#define LOAD_AB(k0)                                                                   \
    {                                                                                 \
        const int kg = (k0) + kh;                                                     \
        const ushort_t* sA = (kg < 128)                                               \
                                 ? (A1 + (size_t)(rb0 + sr) * 128 + kg)               \
                                 : (A2 + (size_t)(rb0 + sr) * 128 + (kg - 128));      \
        pa0 = *(const uint4*)(sA);                                                    \
        pa1 = *(const uint4*)(sA + 8);                                                \
        const ushort_t* sB = Wt + (size_t)(cb0 + sr) * 256 + (k0) + kh;               \
        pb0 = *(const uint4*)(sB);                                                    \
        pb1 = *(const uint4*)(sB + 8);                                                \
    }

    LOAD_AB(0);
#pragma unroll
    for (int t = 0; t < 4; ++t) {
        if (t) __syncthreads();  // all waves done reading previous tile
        *(uint4*)(&As[sr * 72 + kh]) = pa0;
        *(uint4*)(&As[sr * 72 + kh + 8]) = pa1;
        *(uint4*)(&Bs[sr * 72 + kh]) = pb0;
        *(uint4*)(&Bs[sr * 72 + kh + 8]) = pb1;
        __syncthreads();
        if (t < 3) LOAD_AB((t + 1) * 64);  // prefetch next tile under compute
#pragma unroll
        for (int ks = 0; ks < 2; ++ks) {
            const int ko = ks * 32 + q * 8;
            bf16x8 a0 = *(const bf16x8*)&As[(wv * 16 + l15) * 72 + ko];
#pragma unroll
            for (int j = 0; j < 8; ++j) {
                bf16x8 b = *(const bf16x8*)&Bs[(j * 16 + l15) * 72 + ko];
                acc[j] = __builtin_amdgcn_mfma_f32_16x16x32_bf16(a0, b, acc[j], 0, 0, 0);
            }
        }
    }
#undef LOAD_AB

    // C/D: col = j*16 + l15, row = rb0 + wv*16 + q*4 + v
    if (mode == 0) {
        float bv[8];
#pragma unroll
        for (int j = 0; j < 8; ++j) bv[j] = bz[j * 16 + l15];
#pragma unroll
        for (int j = 0; j < 8; ++j)
#pragma unroll
            for (int v = 0; v < 4; ++v) {
                int row = rb0 + wv * 16 + q * 4 + v;
                z_out[(size_t)row * 128 + j * 16 + l15] = f2b(sigm(acc[j][v] + bv[j]));
            }
    } else if (mode == 1) {
        float bv[8];
#pragma unroll
        for (int j = 0; j < 8; ++j) bv[j] = br[j * 16 + l15];
#pragma unroll
        for (int j = 0; j < 8; ++j)
#pragma unroll
            for (int v = 0; v < 4; ++v) {
                int row = rb0 + wv * 16 + q * 4 + v;
                float r = sigm(acc[j][v] + bv[j]);
                float hh = h_prev[(size_t)row * 128 + j * 16 + l15];
                rh_out[(size_t)row * 128 + j * 16 + l15] = f2b(r * hh);
            }
    } else {
        float bv[8], gv[8], bev[8];
#pragma unroll
        for (int j = 0; j < 8; ++j) {
            bv[j] = bc[j * 16 + l15];
            gv[j] = gamma[j * 16 + l15];
            bev[j] = beta[j * 16 + l15];
        }
#pragma unroll
        for (int v = 0; v < 4; ++v) {
            const int row = rb0 + wv * 16 + q * 4 + v;
            float hn[8];
            float s = 0.f;
#pragma unroll
            for (int j = 0; j < 8; ++j) {
                float hc = tanh_fast(acc[j][v] + bv[j]);
                float zz = b2f((uint_t)z_in[(size_t)row * 128 + j * 16 + l15]);
                float hh = h_prev[(size_t)row * 128 + j * 16 + l15];
                hn[j] = (1.0f - zz) * hh + zz * hc;
                s += hn[j];
            }
#pragma unroll
            for (int o = 8; o > 0; o >>= 1) s += __shfl_xor(s, o);  // 16-lane quad
            float mu = s * (1.0f / 128.0f);
            float vv = 0.f;
#pragma unroll
            for (int j = 0; j < 8; ++j) {
                float d = hn[j] - mu;
                vv += d * d;
            }
#pragma unroll
            for (int o = 8; o > 0; o >>= 1) vv += __shfl_xor(vv, o);
            float inv = rsqrtf(vv * (1.0f / 128.0f) + LN_EPS);
#pragma unroll
            for (int j = 0; j < 8; ++j)
                f_out[(size_t)row * 128 + j * 16 + l15] =
                    (hn[j] - mu) * inv * gv[j] + bev[j];
        }
    }
}

// ---------------- launch ----------------

extern "C" void kernel_launch(void* const* d_in, const int* in_sizes, int n_in,
                              void* d_out, int out_size, void* d_ws, size_t ws_size,
                              hipStream_t stream) {
    const float* x = (const float*)d_in[0];
    const int* ei = (const int*)d_in[1];
    const float* h = (const float*)d_in[2];
    const float* Wz = (const float*)d_in[3];
    const float* bz = (const float*)d_in[4];
    const float* Wr = (const float*)d_in[5];
    const float* br = (const float*)d_in[6];
    const float* Wc = (const float*)d_in[7];
    const float* bcv = (const float*)d_in[8];
    const float* gamma = (const float*)d_in[9];
    const float* beta = (const float*)d_in[10];
    float* out = (float*)d_out;

    char* w = (char*)d_ws;
    int* offs = (int*)(w + 0);                    //    40,004 B
    float* dis = (float*)(w + 40960);             //    40,000 B
    int* csr_pk = (int*)(w + 81920);              //   640,000 B (w<<16|src packed)
    int* order = (int*)(w + 721920);              //    40,000 B (degree-sorted nodes)
    int* hist = (int*)(w + 765952);               //       256 B (64 degree buckets)
    int* bcur = (int*)(w + 766208);               //       256 B (bucket cursors)
    ushort_t* Wt_zr = (ushort_t*)(w + 1041920);   //   131,072 B
    ushort_t* Wt_c = (ushort_t*)(w + 1172992);    //    65,536 B
    ushort_t* xb = (ushort_t*)(w + 1239040);      // 20,480,000 B
    ushort_t* hb = (ushort_t*)(w + 21719040);     // 20,480,000 B
    ushort_t* agg_x = (ushort_t*)(w + 42199040);  // 20,480,000 B
    ushort_t* agg_h = (ushort_t*)(w + 62679040);  // 20,480,000 B -> end 83,159,040
    // aliases (strict lifetime reuse on one stream):
    int* cnt = (int*)(w + 1239040);     // dead after fill_csr, before packwt_k
    int* cursor = (int*)(w + 1280000);  // dead after fill_csr
    int* bsum = (int*)(w + 1320000);    // dead after scan3
    ushort_t* z_buf = xb;      // xb dead after gather16<2>; written by gemm<0>
    ushort_t* rh_bf = hb;      // hb dead after gather16<2>; written by gemm<0>
    ushort_t* agg_rh = agg_h;  // agg_h dead after gemm<0>

    hipMemsetAsync(cnt, 0, NN * sizeof(int), stream);
    hipMemsetAsync(hist, 0, 64 * sizeof(int), stream);
    count_deg<<<EE / 256, 256, 0, stream>>>(ei, cnt);
    scan1<<<40, 256, 0, stream>>>(cnt, offs, bsum);
    scan3<<<40, 256, 0, stream>>>(cnt, bsum, offs, cursor, dis, hist);
    bucket_scan<<<1, 64, 0, stream>>>(hist, bcur);
    fill_csr<<<EE / 256, 256, 0, stream>>>(ei, cursor, dis, csr_pk);
    order_k<<<40, 256, 0, stream>>>(offs, bcur, order);
    packwt_k<<<10384, 256, 0, stream>>>(x, h, xb, hb, Wz, Wr, Wc, Wt_zr, Wt_c);

    // agg_x, agg_h in one fused pass: 16 sorted nodes per block, batch = blockIdx&7
    gather16<2><<<(NN / 16) * 8, 256, 0, stream>>>(xb, hb, offs, csr_pk, dis, order,
                                                   agg_x, agg_h);
    // z (y=0) and rh (y=1) from one GEMM over [agg_x|agg_h]
    gemm_k<0><<<dim3(80000 / 128, 2), 512, 0, stream>>>(
        agg_x, agg_h, Wt_zr, bz, br, bcv, h, (const ushort_t*)0, gamma, beta,
        z_buf, rh_bf, (float*)0);
    gather16<1><<<(NN / 16) * 8, 256, 0, stream>>>(rh_bf, (const ushort_t*)0, offs,
                                                   csr_pk, dis, order, agg_rh,
                                                   (ushort_t*)0);
    // out = LN(GRU(tanh([agg_x|agg_rh]@Wc + bc)))
    gemm_k<1><<<dim3(80000 / 128, 1), 512, 0, stream>>>(
        agg_x, agg_rh, Wt_c, bz, br, bcv, h, z_buf, gamma, beta,
        (ushort_t*)0, (ushort_t*)0, out);
}

// Round 8
// 285.514 us; speedup vs baseline: 1.2161x; 1.2161x over previous
//
#include <hip/hip_runtime.h>

#define NN 10000
#define BB 8
#define EE 160000
#define DH 128
#define LN_EPS 1e-5f

typedef unsigned short ushort_t;
typedef unsigned int uint_t;

typedef __bf16 bf16x8 __attribute__((ext_vector_type(8)));
typedef float floatx4 __attribute__((ext_vector_type(4)));
typedef float floatx2 __attribute__((ext_vector_type(2)));

__device__ __forceinline__ float b2f(uint_t u) { return __uint_as_float(u << 16); }
__device__ __forceinline__ ushort_t f2b(float f) {
    uint_t u = __float_as_uint(f);
    return (ushort_t)((u + 0x7fffu + ((u >> 16) & 1u)) >> 16);
}
__device__ __forceinline__ uint_t pack2(float lo, float hi) {
    return (uint_t)f2b(lo) | ((uint_t)f2b(hi) << 16);
}
__device__ __forceinline__ float sigm(float x) { return 1.0f / (1.0f + __expf(-x)); }
__device__ __forceinline__ float tanh_fast(float x) {
    float ex = __expf(2.0f * x);
    return 1.0f - 2.0f / (ex + 1.0f);
}

// unpack u32 holding 2 bf16 -> float2
__device__ __forceinline__ floatx2 unpk(uint_t u) {
    floatx2 r;
    r.x = __uint_as_float(u << 16);
    r.y = __uint_as_float(u & 0xffff0000u);
    return r;
}
// packed dual-FMA: a += w * v  (one VALU inst per 2 floats)
__device__ __forceinline__ void pk_fma(floatx2& a, floatx2 w, floatx2 v) {
    asm("v_pk_fma_f32 %0, %1, %2, %0" : "+v"(a) : "v"(w), "v"(v));
}
// accumulate 8 bf16 (uint4) with packed weight w2: 8 unpack + 4 pk_fma
__device__ __forceinline__ void acc8p(floatx2* a, floatx2 w2, uint4 v) {
    pk_fma(a[0], w2, unpk(v.x));
    pk_fma(a[1], w2, unpk(v.y));
    pk_fma(a[2], w2, unpk(v.z));
    pk_fma(a[3], w2, unpk(v.w));
}

// ---------------- CSR build ----------------

__global__ __launch_bounds__(256) void scan1(const int* __restrict__ cnt,
                                             int* __restrict__ offs,
                                             int* __restrict__ bsum) {
    __shared__ int s[256];
    const int t = threadIdx.x, idx = blockIdx.x * 256 + t;
    int x = (idx < NN) ? cnt[idx] : 0;
    s[t] = x;
    __syncthreads();
    for (int o = 1; o < 256; o <<= 1) {
        int v = s[t];
        int u = (t >= o) ? s[t - o] : 0;
        __syncthreads();
        s[t] = v + u;
        __syncthreads();
    }
    if (idx < NN) offs[idx] = s[t] - x;  // block-local exclusive
    if (t == 255) bsum[blockIdx.x] = s[255];
}

// scan3 also does the cross-block prefix (scan2 fused away)
__global__ __launch_bounds__(256) void scan3(const int* __restrict__ cnt,
                                             const int* __restrict__ bsum,
                                             int* __restrict__ offs,
                                             int* __restrict__ cursor,
                                             float* __restrict__ dis) {
    __shared__ int sb[40];
    __shared__ int pfx;
    const int t = threadIdx.x;
    if (t < 40) sb[t] = bsum[t];
    __syncthreads();
    if (t == 0) {
        int a = 0;
        for (int i = 0; i < blockIdx.x; ++i) a += sb[i];
        pfx = a;
    }
    __syncthreads();
    const int idx = blockIdx.x * 256 + t;
    if (idx < NN) {
        int off = offs[idx] + pfx;
        offs[idx] = off;
        cursor[idx] = off;
        dis[idx] = rsqrtf((float)(cnt[idx] + 1));
    }
    if (idx == 0) offs[NN] = EE;
}

// csr packed: bf16(dis[src])<<16 | src   (src < 16384 fits 14 bits)
__global__ void fill_csr(const int* __restrict__ ei, int* __restrict__ cursor,
                         const float* __restrict__ dis, int* __restrict__ csr_pk) {
    int e = blockIdx.x * 256 + threadIdx.x;
    if (e < EE) {
        int s = ei[e];
        int d = ei[EE + e];
        int pos = atomicAdd(&cursor[d], 1);
        csr_pk[pos] = (int)(((uint_t)f2b(dis[s]) << 16) | (uint_t)s);
    }
}

// ---------------- merged: count_deg (blocks 0..624) | pack x,h + Wt (rest) --------
// count_deg and packwt are mutually independent -> one dispatch, overlapped.
// NOTE: cnt/cursor/bsum must NOT alias xb (pack now runs concurrently/before them).

__global__ __launch_bounds__(256) void cp_k(const int* __restrict__ ei,
                                            int* __restrict__ cnt,
                                            const float* __restrict__ x,
                                            const float* __restrict__ h,
                                            ushort_t* __restrict__ xb,
                                            ushort_t* __restrict__ hb,
                                            const float* __restrict__ Wz,
                                            const float* __restrict__ Wr,
                                            const float* __restrict__ Wc,
                                            ushort_t* __restrict__ Wt_zr,
                                            ushort_t* __restrict__ Wt_c) {
    if (blockIdx.x < 625) {  // count_deg: 625*256 = 160000 = EE
        int e = blockIdx.x * 256 + threadIdx.x;
        atomicAdd(&cnt[ei[EE + e]], 1);
        return;
    }
    const int bid = blockIdx.x - 625;
    if (bid < 10000) {
        const size_t o = ((size_t)bid * 256 + threadIdx.x) * 4;
        float4 vx = *(const float4*)(x + o);
        uint2 px;
        px.x = pack2(vx.x, vx.y);
        px.y = pack2(vx.z, vx.w);
        *(uint2*)(xb + o) = px;
        float4 vh = *(const float4*)(h + o);
        uint2 ph;
        ph.x = pack2(vh.x, vh.y);
        ph.y = pack2(vh.z, vh.w);
        *(uint2*)(hb + o) = ph;
    } else {
        const int col = bid - 10000, k = threadIdx.x;
        if (col < 256) {
            float v = (col < 128) ? Wz[(size_t)k * 128 + col]
                                  : Wr[(size_t)k * 128 + col - 128];
            Wt_zr[(size_t)col * 256 + k] = f2b(v);
        } else {
            int c2 = col - 256;
            Wt_c[(size_t)c2 * 256 + k] = f2b(Wc[(size_t)k * 128 + c2]);
        }
    }
}

// ---------------- gather16: 4 waves x 4 nodes/wave, 16 lanes per node -------------
// dst[b,n] = dis[n] * ( sum_e dis[s]*src[b,s] + dis[n]*src[b,n] )
// One 16-lane group per node: lane il owns cols il*8..il*8+7, accumulates ALL edges
// of its node -> lane-private result, no cross-lane reduce. b = blockIdx&7 keeps
// XCD/L2 batch sharding (FETCH ~104 MB). Packed CSR word (w<<16|src) -> ONE
// bpermute per edge; junk slots broadcast 0 -> weight 0.0 -> no predication.
// 8 edges batched per step: 16 uint4 loads in flight (NB=2) before any FMA.

template <int NB>
__global__ __launch_bounds__(256) void gather16(
    const ushort_t* __restrict__ src0, const ushort_t* __restrict__ src1,
    const int* __restrict__ offs, const int* __restrict__ csr_pk,
    const float* __restrict__ dis, ushort_t* __restrict__ dst0,
    ushort_t* __restrict__ dst1) {
    const int tid = threadIdx.x, lane = tid & 63;
    const int b = blockIdx.x & 7;
    const int g = lane >> 4, il = lane & 15;
    const int ng = (blockIdx.x >> 3) * 16 + (tid >> 6) * 4 + g;  // my group's node
    const ushort_t* base0 = src0 + (size_t)b * NN * 128;
    const ushort_t* base1 = (NB == 2) ? (src1 + (size_t)b * NN * 128) : base0;
    const uint_t cofs = (uint_t)il * 8u;

    floatx2 a0[4], a1[4];
#pragma unroll
    for (int j = 0; j < 4; ++j) {
        a0[j] = (floatx2){0.f, 0.f};
        a1[j] = (floatx2){0.f, 0.f};
    }

    const int e0 = offs[ng], e1 = offs[ng + 1];
    const float dn = dis[ng];

    {  // self row, weight dn inside the sum
        const floatx2 d2 = {dn, dn};
        const uint_t off = (uint_t)ng * 128u + cofs;
        acc8p(a0, d2, *(const uint4*)(base0 + off));
        if (NB == 2) acc8p(a1, d2, *(const uint4*)(base1 + off));
    }

    // max degree over the wave's 4 groups -> uniform loop bound
    int mx = e1 - e0;
    mx = max(mx, __shfl_xor(mx, 16));
    mx = max(mx, __shfl_xor(mx, 32));
    const int dmax = __builtin_amdgcn_readfirstlane(mx);
    const int pbase = (lane & 48) << 2;  // bpermute byte base of group's lane 0

    for (int ibase = 0; ibase < dmax; ibase += 16) {
        // refill: lane il of group g holds packed edge e0+ibase+il (0 if past end)
        int pk = 0;
        const int pos = e0 + ibase + il;
        if (pos < e1) pk = csr_pk[pos];
        const int lim = (dmax - ibase) < 16 ? (dmax - ibase) : 16;

        // 8 edges per step: all metadata, then all loads, then all FMAs
#define PROC8(OFF)                                                                   \
    {                                                                                \
        int p[8];                                                                    \
        uint_t q[8];                                                                 \
        _Pragma("unroll") for (int k = 0; k < 8; ++k) p[k] =                         \
            __builtin_amdgcn_ds_bpermute(pbase + ((OFF) + k) * 4, pk);               \
        _Pragma("unroll") for (int k = 0; k < 8; ++k) q[k] =                         \
            (uint_t)(p[k] & 0xffff) * 128u + cofs;                                   \
        uint4 v[8];                                                                  \
        _Pragma("unroll") for (int k = 0; k < 8; ++k) v[k] =                         \
            *(const uint4*)(base0 + q[k]);                                           \
        uint4 u[8];                                                                  \
        if (NB == 2) {                                                               \
            _Pragma("unroll") for (int k = 0; k < 8; ++k) u[k] =                     \
                *(const uint4*)(base1 + q[k]);                                       \
        }                                                                            \
        _Pragma("unroll") for (int k = 0; k < 8; ++k) {                              \
            const float f = __uint_as_float((uint_t)p[k] & 0xffff0000u);             \
            const floatx2 w2 = {f, f};                                               \
            acc8p(a0, w2, v[k]);                                                     \
            if (NB == 2) acc8p(a1, w2, u[k]);                                        \
        }                                                                            \
    }
        PROC8(0);
        if (lim > 8) PROC8(8);
#undef PROC8
    }

    // lane-private result: scale by dn, pack, store (all 64 lanes)
    const size_t o = ((size_t)b * NN + ng) * 128 + cofs;
    uint4 st;
    st.x = pack2(a0[0].x * dn, a0[0].y * dn);
    st.y = pack2(a0[1].x * dn, a0[1].y * dn);
    st.z = pack2(a0[2].x * dn, a0[2].y * dn);
    st.w = pack2(a0[3].x * dn, a0[3].y * dn);
    *(uint4*)(dst0 + o) = st;
    if (NB == 2) {
        uint4 st1;
        st1.x = pack2(a1[0].x * dn, a1[0].y * dn);
        st1.y = pack2(a1[1].x * dn, a1[1].y * dn);
        st1.z = pack2(a1[2].x * dn, a1[2].y * dn);
        st1.w = pack2(a1[3].x * dn, a1[3].y * dn);
        *(uint4*)(dst1 + o) = st1;
    }
}

// ---------------- GEMM 128x128 tile, K=256 = [A1 | A2] @ Wt, fused epilogues ------
// 512 threads / 8 waves: wave w owns rows w*16..w*16+15 (acc = 8 x floatx4).
// Register-prefetch pipeline: k0+1's global loads issued before k0's MFMA compute,
// consumed by ds_write after the next barrier -> HBM latency hidden under compute.
// PHASE 0: mode=blockIdx.y (0: z=sigma->z_buf bf16; 1: r=sigma, rh=r*h->rh bf16)
// PHASE 1: mode 2: tanh, GRU blend, LayerNorm -> out f32

template <int PHASE>
__global__ __launch_bounds__(512) void gemm_k(
    const ushort_t* __restrict__ A1, const ushort_t* __restrict__ A2,
    const ushort_t* __restrict__ Wt, const float* __restrict__ bz,
    const float* __restrict__ br, const float* __restrict__ bc,
    const float* __restrict__ h_prev, const ushort_t* __restrict__ z_in,
    const float* __restrict__ gamma, const float* __restrict__ beta,
    ushort_t* __restrict__ z_out, ushort_t* __restrict__ rh_out,
    float* __restrict__ f_out) {
    __shared__ __align__(16) ushort_t As[128 * 72];
    __shared__ __align__(16) ushort_t Bs[128 * 72];
    const int tid = threadIdx.x;
    const int rb0 = blockIdx.x * 128;
    const int mode = (PHASE == 1) ? 2 : blockIdx.y;
    const int cb0 = (mode == 1) ? 128 : 0;

    const int wv = tid >> 6, lane = tid & 63;
    const int l15 = lane & 15, q = lane >> 4;
    const int sr = tid >> 2;        // 0..127: A row / B col staged by this thread
    const int kh = (tid & 3) * 16;  // 16-element K chunk

    floatx4 acc[8];
#pragma unroll
    for (int j = 0; j < 8; ++j) acc[j] = (floatx4){0.f, 0.f, 0.f, 0.f};

    uint4 pa0, pa1, pb0, pb1;  // prefetch registers (one K-step tile slice)
#define LOAD_AB(k0)                                                                   \
    {                                                                                 \
        const int kg = (k0) + kh;                                                     \
        const ushort_t* sA = (kg < 128)                                               \
                                 ? (A1 + (size_t)(rb0 + sr) * 128 + kg)               \
                                 : (A2 + (size_t)(rb0 + sr) * 128 + (kg - 128));      \
        pa0 = *(const uint4*)(sA);                                                    \
        pa1 = *(const uint4*)(sA + 8);                                                \
        const ushort_t* sB = Wt + (size_t)(cb0 + sr) * 256 + (k0) + kh;               \
        pb0 = *(const uint4*)(sB);                                                    \
        pb1 = *(const uint4*)(sB + 8);                                                \
    }

    LOAD_AB(0);
#pragma unroll
    for (int t = 0; t < 4; ++t) {
        if (t) __syncthreads();  // all waves done reading previous tile
        *(uint4*)(&As[sr * 72 + kh]) = pa0;
        *(uint4*)(&As[sr * 72 + kh + 8]) = pa1;
        *(uint4*)(&Bs[sr * 72 + kh]) = pb0;
        *(uint4*)(&Bs[sr * 72 + kh + 8]) = pb1;
        __syncthreads();
        if (t < 3) LOAD_AB((t + 1) * 64);  // prefetch next tile under compute
#pragma unroll
        for (int ks = 0; ks < 2; ++ks) {
            const int ko = ks * 32 + q * 8;
            bf16x8 a0 = *(const bf16x8*)&As[(wv * 16 + l15) * 72 + ko];
#pragma unroll
            for (int j = 0; j < 8; ++j) {
                bf16x8 b = *(const bf16x8*)&Bs[(j * 16 + l15) * 72 + ko];
                acc[j] = __builtin_amdgcn_mfma_f32_16x16x32_bf16(a0, b, acc[j], 0, 0, 0);
            }
        }
    }
#undef LOAD_AB

    // C/D: col = j*16 + l15, row = rb0 + wv*16 + q*4 + v
    if (mode == 0) {
        float bv[8];
#pragma unroll
        for (int j = 0; j < 8; ++j) bv[j] = bz[j * 16 + l15];
#pragma unroll
        for (int j = 0; j < 8; ++j)
#pragma unroll
            for (int v = 0; v < 4; ++v) {
                int row = rb0 + wv * 16 + q * 4 + v;
                z_out[(size_t)row * 128 + j * 16 + l15] = f2b(sigm(acc[j][v] + bv[j]));
            }
    } else if (mode == 1) {
        float bv[8];
#pragma unroll
        for (int j = 0; j < 8; ++j) bv[j] = br[j * 16 + l15];
#pragma unroll
        for (int j = 0; j < 8; ++j)
#pragma unroll
            for (int v = 0; v < 4; ++v) {
                int row = rb0 + wv * 16 + q * 4 + v;
                float r = sigm(acc[j][v] + bv[j]);
                float hh = h_prev[(size_t)row * 128 + j * 16 + l15];
                rh_out[(size_t)row * 128 + j * 16 + l15] = f2b(r * hh);
            }
    } else {
        float bv[8], gv[8], bev[8];
#pragma unroll
        for (int j = 0; j < 8; ++j) {
            bv[j] = bc[j * 16 + l15];
            gv[j] = gamma[j * 16 + l15];
            bev[j] = beta[j * 16 + l15];
        }
#pragma unroll
        for (int v = 0; v < 4; ++v) {
            const int row = rb0 + wv * 16 + q * 4 + v;
            float hn[8];
            float s = 0.f;
#pragma unroll
            for (int j = 0; j < 8; ++j) {
                float hc = tanh_fast(acc[j][v] + bv[j]);
                float zz = b2f((uint_t)z_in[(size_t)row * 128 + j * 16 + l15]);
                float hh = h_prev[(size_t)row * 128 + j * 16 + l15];
                hn[j] = (1.0f - zz) * hh + zz * hc;
                s += hn[j];
            }
#pragma unroll
            for (int o = 8; o > 0; o >>= 1) s += __shfl_xor(s, o);  // 16-lane quad
            float mu = s * (1.0f / 128.0f);
            float vv = 0.f;
#pragma unroll
            for (int j = 0; j < 8; ++j) {
                float d = hn[j] - mu;
                vv += d * d;
            }
#pragma unroll
            for (int o = 8; o > 0; o >>= 1) vv += __shfl_xor(vv, o);
            float inv = rsqrtf(vv * (1.0f / 128.0f) + LN_EPS);
#pragma unroll
            for (int j = 0; j < 8; ++j)
                f_out[(size_t)row * 128 + j * 16 + l15] =
                    (hn[j] - mu) * inv * gv[j] + bev[j];
        }
    }
}

// ---------------- launch ----------------

extern "C" void kernel_launch(void* const* d_in, const int* in_sizes, int n_in,
                              void* d_out, int out_size, void* d_ws, size_t ws_size,
                              hipStream_t stream) {
    const float* x = (const float*)d_in[0];
    const int* ei = (const int*)d_in[1];
    const float* h = (const float*)d_in[2];
    const float* Wz = (const float*)d_in[3];
    const float* bz = (const float*)d_in[4];
    const float* Wr = (const float*)d_in[5];
    const float* br = (const float*)d_in[6];
    const float* Wc = (const float*)d_in[7];
    const float* bcv = (const float*)d_in[8];
    const float* gamma = (const float*)d_in[9];
    const float* beta = (const float*)d_in[10];
    float* out = (float*)d_out;

    char* w = (char*)d_ws;
    int* offs = (int*)(w + 0);                    //    40,004 B
    float* dis = (float*)(w + 40960);             //    40,000 B
    int* csr_pk = (int*)(w + 81920);              //   640,000 B (w<<16|src packed)
    int* cnt = (int*)(w + 721920);                //    40,000 B (NOT aliased: cp_k
    int* cursor = (int*)(w + 762880);             //    40,000 B  packs xb before/
    int* bsum = (int*)(w + 803840);               //       160 B  while these live)
    ushort_t* Wt_zr = (ushort_t*)(w + 1041920);   //   131,072 B
    ushort_t* Wt_c = (ushort_t*)(w + 1172992);    //    65,536 B
    ushort_t* xb = (ushort_t*)(w + 1239040);      // 20,480,000 B
    ushort_t* hb = (ushort_t*)(w + 21719040);     // 20,480,000 B
    ushort_t* agg_x = (ushort_t*)(w + 42199040);  // 20,480,000 B
    ushort_t* agg_h = (ushort_t*)(w + 62679040);  // 20,480,000 B -> end 83,159,040
    // aliases (strict lifetime reuse on one stream):
    ushort_t* z_buf = xb;      // xb dead after gather16<2>; written by gemm<0>
    ushort_t* rh_bf = hb;      // hb dead after gather16<2>; written by gemm<0>
    ushort_t* agg_rh = agg_h;  // agg_h dead after gemm<0>

    hipMemsetAsync(cnt, 0, NN * sizeof(int), stream);
    // count_deg (625 blocks) | pack x,h -> bf16 + weight transpose (10384 blocks)
    cp_k<<<11009, 256, 0, stream>>>(ei, cnt, x, h, xb, hb, Wz, Wr, Wc, Wt_zr, Wt_c);
    scan1<<<40, 256, 0, stream>>>(cnt, offs, bsum);
    scan3<<<40, 256, 0, stream>>>(cnt, bsum, offs, cursor, dis);
    fill_csr<<<EE / 256, 256, 0, stream>>>(ei, cursor, dis, csr_pk);

    // agg_x, agg_h in one fused pass: 16 nodes per block, batch = blockIdx&7
    gather16<2><<<(NN / 16) * 8, 256, 0, stream>>>(xb, hb, offs, csr_pk, dis,
                                                   agg_x, agg_h);
    // z (y=0) and rh (y=1) from one GEMM over [agg_x|agg_h]
    gemm_k<0><<<dim3(80000 / 128, 2), 512, 0, stream>>>(
        agg_x, agg_h, Wt_zr, bz, br, bcv, h, (const ushort_t*)0, gamma, beta,
        z_buf, rh_bf, (float*)0);
    gather16<1><<<(NN / 16) * 8, 256, 0, stream>>>(rh_bf, (const ushort_t*)0, offs,
                                                   csr_pk, dis, agg_rh,
                                                   (ushort_t*)0);
    // out = LN(GRU(tanh([agg_x|agg_rh]@Wc + bc)))
    gemm_k<1><<<dim3(80000 / 128, 1), 512, 0, stream>>>(
        agg_x, agg_rh, Wt_c, bz, br, bcv, h, z_buf, gamma, beta,
        (ushort_t*)0, (ushort_t*)0, out);
}